// Round 7
// baseline (9129.411 us; speedup 1.0000x reference)
//
#include <hip/hip_runtime.h>
#include <hip/hip_bf16.h>
#include <math.h>

namespace {
constexpr int kT    = 512;   // seq len
constexpr int kH    = 512;   // hidden
constexpr int kFF   = 2048;
constexpr int kB    = 8;
constexpr int kNTOK = kB * kT;        // 4096
constexpr int kNLAT = kB * kT / 4;    // 1024
constexpr int kK    = 4096;           // codebook size
constexpr int kDP   = 150;
constexpr long kReconN  = (long)kNTOK * kDP;     // 614400
constexpr long kIdxOff  = kReconN;               // 614400
constexpr long kScalOff = kReconN + kNLAT;       // 615424
constexpr long kZeOff   = kScalOff + 3;          // 615427
constexpr long kZeN     = (long)kNLAT * 512;     // 524288
}

// ---------------- small / elementwise kernels ----------------

__global__ __launch_bounds__(256) void zero_scal_kernel(float* s) {
  if (threadIdx.x < 2) s[threadIdx.x] = 0.0f;
}

// PE in float64 (numpy promotes pos*div to f64; sin/cos in f64; stored f32)
__global__ __launch_bounds__(256) void pe_kernel(float* __restrict__ pe) {
  int i = blockIdx.x * 256 + threadIdx.x;      // 262144
  int t = i >> 9, c = i & 511;
  int j2 = c & ~1;
  double div = exp((double)j2 * (-9.210340371976184 / 512.0));
  double a = (double)t * div;
  pe[i] = (float)((c & 1) ? cos(a) : sin(a));
}

__global__ __launch_bounds__(256) void addpe_kernel(float* __restrict__ h, const float* __restrict__ pe) {
  long i = (long)blockIdx.x * 256 + threadIdx.x;    // 2097152
  h[i] += pe[i & (long)(kT * kH - 1)];
}

__global__ __launch_bounds__(256) void qinit_kernel(float* __restrict__ q, const float* __restrict__ qe,
                                                    const float* __restrict__ pe) {
  long i = (long)blockIdx.x * 256 + threadIdx.x;    // 2097152
  long j = i & (long)(kT * kH - 1);
  q[i] = qe[j] + pe[j];
}

__global__ __launch_bounds__(256) void perm_encconv_kernel(const float* __restrict__ w, float* __restrict__ W2) {
  int i = blockIdx.x * 256 + threadIdx.x;       // 1048576
  int e = i >> 11, rem = i & 2047, r = rem >> 9, hh = rem & 511;
  W2[i] = w[e * 2048 + hh * 4 + r];
}

__global__ __launch_bounds__(256) void perm_decup_kernel(const float* __restrict__ w, const float* __restrict__ bvec,
                                                         float* __restrict__ W3, float* __restrict__ B3) {
  int i = blockIdx.x * 256 + threadIdx.x;       // 1048576
  int n = i >> 9, c = i & 511, kk = n >> 9, o = n & 511;
  W3[i] = w[c * 2048 + o * 4 + kk];
  if (c == 0) B3[n] = bvec[o];
}

// ---------------- LayerNorm (double statistics; one block per row of 512) ----------------

__global__ __launch_bounds__(256) void ln_kernel(const float* __restrict__ X, const float* __restrict__ w,
                                                 const float* __restrict__ b, float* __restrict__ Y) {
  __shared__ double red[256];
  long row = blockIdx.x;
  const float* x = X + row * 512;
  float* y = Y + row * 512;
  int tid = threadIdx.x;
  float v0 = x[tid], v1 = x[tid + 256];
  red[tid] = (double)v0 + (double)v1; __syncthreads();
  for (int s = 128; s > 0; s >>= 1) { if (tid < s) red[tid] += red[tid + s]; __syncthreads(); }
  double mean = red[0] * (1.0 / 512.0);
  __syncthreads();
  double d0 = (double)v0 - mean, d1 = (double)v1 - mean;
  red[tid] = d0 * d0 + d1 * d1; __syncthreads();
  for (int s = 128; s > 0; s >>= 1) { if (tid < s) red[tid] += red[tid + s]; __syncthreads(); }
  double var = red[0] * (1.0 / 512.0);
  double inv = 1.0 / sqrt(var + 1e-5);
  y[tid]       = (float)(d0 * inv * (double)w[tid]       + (double)b[tid]);
  y[tid + 256] = (float)(d1 * inv * (double)w[tid + 256] + (double)b[tid + 256]);
}

// ---------------- softmax over rows of 512 (double sums) ----------------

__global__ __launch_bounds__(256) void softmax_rows_kernel(float* __restrict__ S) {
  __shared__ double red[256];
  long row = blockIdx.x;
  float* p = S + row * 512;
  int tid = threadIdx.x;
  float v0 = p[tid], v1 = p[tid + 256];
  red[tid] = (double)fmaxf(v0, v1); __syncthreads();
  for (int s = 128; s > 0; s >>= 1) { if (tid < s) red[tid] = fmax(red[tid], red[tid + s]); __syncthreads(); }
  float m = (float)red[0];
  __syncthreads();
  float e0 = expf(v0 - m), e1 = expf(v1 - m);
  red[tid] = (double)e0 + (double)e1; __syncthreads();
  for (int s = 128; s > 0; s >>= 1) { if (tid < s) red[tid] += red[tid + s]; __syncthreads(); }
  double inv = 1.0 / red[0];
  p[tid] = (float)(e0 * inv); p[tid + 256] = (float)(e1 * inv);
}

// ---------------- generic GEMM: C = alpha * A(M,Kd;lda) @ W(N,Kd;ldw)^T [+bias] [gelu] [+=C] ----
// ACC = float (decoder) or double (encoder)

template <typename ACC>
__global__ __launch_bounds__(256) void gemm_kernel(
    const float* __restrict__ A, int lda, long sAo, long sAi,
    const float* __restrict__ W, int ldw, long sWo, long sWi,
    float* __restrict__ C, int ldc, long sCo, long sCi,
    const float* __restrict__ bias,
    int M, int N, int Kd, int zDiv, float alpha, int flags) {
  int z = blockIdx.z;
  int zo = z / zDiv, zi = z % zDiv;
  A += (long)zo * sAo + (long)zi * sAi;
  W += (long)zo * sWo + (long)zi * sWi;
  C += (long)zo * sCo + (long)zi * sCi;
  __shared__ float As[16][64];
  __shared__ float Ws[16][64];
  int tid = threadIdx.x;
  int tx = tid & 15, ty = tid >> 4;
  int rowBase = blockIdx.y * 64, colBase = blockIdx.x * 64;
  int ldRow = tid >> 2;
  int ldSeg = (tid & 3) << 2;
  bool vec4 = ((lda & 3) == 0) && ((ldw & 3) == 0) && ((Kd & 3) == 0);
  ACC acc[4][4] = {};
  for (int kb = 0; kb < Kd; kb += 16) {
    int ga = rowBase + ldRow;
    int gw = colBase + ldRow;
    if (vec4) {
      float4 va = make_float4(0.f, 0.f, 0.f, 0.f), vw = make_float4(0.f, 0.f, 0.f, 0.f);
      if (ga < M && kb + ldSeg < Kd)
        va = *reinterpret_cast<const float4*>(A + (long)ga * lda + kb + ldSeg);
      if (gw < N && kb + ldSeg < Kd)
        vw = *reinterpret_cast<const float4*>(W + (long)gw * ldw + kb + ldSeg);
      As[ldSeg + 0][ldRow] = va.x; As[ldSeg + 1][ldRow] = va.y;
      As[ldSeg + 2][ldRow] = va.z; As[ldSeg + 3][ldRow] = va.w;
      Ws[ldSeg + 0][ldRow] = vw.x; Ws[ldSeg + 1][ldRow] = vw.y;
      Ws[ldSeg + 2][ldRow] = vw.z; Ws[ldSeg + 3][ldRow] = vw.w;
    } else {
#pragma unroll
      for (int q = 0; q < 4; ++q) {
        int k = kb + ldSeg + q;
        As[ldSeg + q][ldRow] = (ga < M && k < Kd) ? A[(long)ga * lda + k] : 0.f;
        Ws[ldSeg + q][ldRow] = (gw < N && k < Kd) ? W[(long)gw * ldw + k] : 0.f;
      }
    }
    __syncthreads();
#pragma unroll
    for (int kk = 0; kk < 16; ++kk) {
      ACC a[4], w[4];
#pragma unroll
      for (int u = 0; u < 4; ++u) { a[u] = (ACC)As[kk][(ty << 2) + u]; w[u] = (ACC)Ws[kk][(tx << 2) + u]; }
#pragma unroll
      for (int i2 = 0; i2 < 4; ++i2)
#pragma unroll
        for (int j2 = 0; j2 < 4; ++j2)
          acc[i2][j2] += a[i2] * w[j2];
    }
    __syncthreads();
  }
#pragma unroll
  for (int i2 = 0; i2 < 4; ++i2) {
    int r = rowBase + (ty << 2) + i2;
    if (r >= M) continue;
#pragma unroll
    for (int j2 = 0; j2 < 4; ++j2) {
      int cidx = colBase + (tx << 2) + j2;
      if (cidx >= N) continue;
      ACC v = (ACC)alpha * acc[i2][j2];
      if (bias) v += (ACC)bias[cidx];
      if (flags & 2) {
        if constexpr (sizeof(ACC) == 8)
          v = 0.5 * v * (1.0 + erf((double)v * 0.7071067811865475244));
        else
          v = 0.5f * v * (1.0f + erff((float)v * 0.7071067811865475f));
      }
      long o = (long)r * ldc + cidx;
      if (flags & 1) v += (ACC)C[o];
      C[o] = (float)v;
    }
  }
}

// ---------------- attention P @ V (one batch, 8 heads via blockIdx.z) ----------------

template <typename ACC>
__global__ __launch_bounds__(256) void pv_kernel(const float* __restrict__ P, const float* __restrict__ V,
                                                 float* __restrict__ O) {
  int h = blockIdx.z;            // 0..7
  const float* Pz = P + (long)h * (kT * kT);
  const float* Vz = V + h * 64;
  float* Oz = O + h * 64;
  int ib = blockIdx.x * 64;
  __shared__ float Ps[16][64];
  __shared__ float Vs[16][64];
  int tid = threadIdx.x;
  int tx = tid & 15, ty = tid >> 4;
  ACC acc[4][4] = {};
  for (int jb = 0; jb < kT; jb += 16) {
    {
      int i = tid >> 2;
      int seg = (tid & 3) << 2;
      float4 v = *reinterpret_cast<const float4*>(Pz + (long)(ib + i) * kT + jb + seg);
      Ps[seg + 0][i] = v.x; Ps[seg + 1][i] = v.y; Ps[seg + 2][i] = v.z; Ps[seg + 3][i] = v.w;
      int j = tid >> 4;           // 0..15
      int dseg = (tid & 15) << 2; // 0..60
      float4 w = *reinterpret_cast<const float4*>(Vz + (long)(jb + j) * kH + dseg);
      *reinterpret_cast<float4*>(&Vs[j][dseg]) = w;
    }
    __syncthreads();
#pragma unroll
    for (int kk = 0; kk < 16; ++kk) {
      ACC a[4], w[4];
#pragma unroll
      for (int u = 0; u < 4; ++u) { a[u] = (ACC)Ps[kk][(ty << 2) + u]; w[u] = (ACC)Vs[kk][(tx << 2) + u]; }
#pragma unroll
      for (int i2 = 0; i2 < 4; ++i2)
#pragma unroll
        for (int j2 = 0; j2 < 4; ++j2)
          acc[i2][j2] += a[i2] * w[j2];
    }
    __syncthreads();
  }
#pragma unroll
  for (int i2 = 0; i2 < 4; ++i2)
#pragma unroll
    for (int j2 = 0; j2 < 4; ++j2)
      Oz[(long)(ib + (ty << 2) + i2) * kH + (tx << 2) + j2] = (float)acc[i2][j2];
}

// ---------------- strided conv -> z_e, f64 accumulation (one block per latent row) ----------------

__global__ __launch_bounds__(256) void conv_ze_kernel(const float* __restrict__ Y, const float* __restrict__ W2,
                                                      const float* __restrict__ bias, float* __restrict__ ZE) {
  __shared__ float ys[2048];
  int m = blockIdx.x;            // 0..1023
  int tid = threadIdx.x;
  for (int k = tid; k < 2048; k += 256) ys[k] = Y[(long)m * 2048 + k];
  __syncthreads();
  for (int e = tid; e < 512; e += 256) {
    const float* w = W2 + (long)e * 2048;
    double acc = 0.0;
    for (int k = 0; k < 2048; k += 4) {
      float4 wv = *reinterpret_cast<const float4*>(w + k);
      acc += (double)ys[k] * wv.x + (double)ys[k + 1] * wv.y
           + (double)ys[k + 2] * wv.z + (double)ys[k + 3] * wv.w;
    }
    ZE[(long)m * 512 + e] = (float)(acc + (double)bias[e]);
  }
}

// ---------------- VQ: emulate numpy's f32 distance bucketing ----------------
// np: dist = f32(|z|^2) + f32(|c|^2) - f32(2*(z@c)) with ops rounded to f32.
// |z|^2 ~ 2600 -> ulp 2.44e-4 buckets; argmin = first (lowest-index) min.

__global__ __launch_bounds__(256) void codenorm_f_kernel(const float* __restrict__ cb, float* __restrict__ cnf) {
  __shared__ double red[256];
  int j = blockIdx.x;
  const float* c = cb + (long)j * 512;
  int tid = threadIdx.x;
  float s0 = c[tid] * c[tid];           // f32 square like np's cb*cb
  float s1 = c[tid + 256] * c[tid + 256];
  red[tid] = (double)s0 + (double)s1; __syncthreads();
  for (int s = 128; s > 0; s >>= 1) { if (tid < s) red[tid] += red[tid + s]; __syncthreads(); }
  if (tid == 0) cnf[j] = (float)red[0];
}

#define VQROWS 8
__global__ __launch_bounds__(256) void vq_kernel(const float* __restrict__ ze, const float* __restrict__ cb,
                                                 const float* __restrict__ cnf,
                                                 int* __restrict__ idx_out, float* __restrict__ idx_f) {
  __shared__ float zs[VQROWS][512];
  __shared__ float Afs[VQROWS];
  __shared__ double redd[256];
  __shared__ float bv[256];
  __shared__ int bis[256];
  int r0 = blockIdx.x * VQROWS;
  int tid = threadIdx.x;
#pragma unroll
  for (int r = 0; r < VQROWS; ++r) {
    zs[r][tid]       = ze[(long)(r0 + r) * 512 + tid];
    zs[r][tid + 256] = ze[(long)(r0 + r) * 512 + tid + 256];
  }
  __syncthreads();
  // Af per row: f32 of sum of f32 squares (f64 tree; +/-1ulp vs np is a uniform shift)
  for (int r = 0; r < VQROWS; ++r) {
    double part = 0.0;
    for (int k = tid; k < 512; k += 256) { float q = zs[r][k] * zs[r][k]; part += (double)q; }
    redd[tid] = part; __syncthreads();
    for (int s = 128; s > 0; s >>= 1) { if (tid < s) redd[tid] += redd[tid + s]; __syncthreads(); }
    if (tid == 0) Afs[r] = (float)redd[0];
    __syncthreads();
  }
  float best[VQROWS]; int bidx[VQROWS];
#pragma unroll
  for (int r = 0; r < VQROWS; ++r) { best[r] = INFINITY; bidx[r] = 0; }
  for (int j = tid; j < kK; j += 256) {
    const float* c = cb + (long)j * 512;
    double acc[VQROWS];
#pragma unroll
    for (int r = 0; r < VQROWS; ++r) acc[r] = 0.0;
    for (int k = 0; k < 512; k += 4) {
      float4 cv = *reinterpret_cast<const float4*>(c + k);
#pragma unroll
      for (int r = 0; r < VQROWS; ++r) {
        acc[r] += (double)zs[r][k] * cv.x + (double)zs[r][k + 1] * cv.y
                + (double)zs[r][k + 2] * cv.z + (double)zs[r][k + 3] * cv.w;
      }
    }
    float bf = cnf[j];
#pragma unroll
    for (int r = 0; r < VQROWS; ++r) {
      float cf = (float)(2.0 * acc[r]);   // f32(2*z.c)
      float t  = Afs[r] + bf;             // f32 add (absorbs bf)
      float d  = t - cf;                  // f32 subtract -> 2.44e-4 buckets
      if (d < best[r]) { best[r] = d; bidx[r] = j; }   // strict < keeps lowest j per thread
    }
  }
#pragma unroll
  for (int r = 0; r < VQROWS; ++r) {
    bv[tid] = best[r]; bis[tid] = bidx[r];
    __syncthreads();
    for (int s = 128; s > 0; s >>= 1) {
      if (tid < s) {
        if (bv[tid + s] < bv[tid] || (bv[tid + s] == bv[tid] && bis[tid + s] < bis[tid])) {
          bv[tid] = bv[tid + s]; bis[tid] = bis[tid + s];
        }
      }
      __syncthreads();
    }
    if (tid == 0) { idx_out[r0 + r] = bis[0]; idx_f[r0 + r] = (float)bis[0]; }
    __syncthreads();
  }
}

__global__ __launch_bounds__(256) void gather_kernel(const float* __restrict__ cb, const int* __restrict__ idx,
                                                     const float* __restrict__ ze, float* __restrict__ zq,
                                                     float* __restrict__ ze_out, float* __restrict__ scal) {
  __shared__ float red[256];
  long i = (long)blockIdx.x * 256 + threadIdx.x;  // 524288
  int row = (int)(i >> 9), c = (int)(i & 511);
  float q = cb[(long)idx[row] * 512 + c];
  float zv = ze[i];
  zq[i] = q;
  ze_out[i] = zv;
  float dsq = (q - zv) * (q - zv);
  red[threadIdx.x] = dsq; __syncthreads();
  for (int s = 128; s > 0; s >>= 1) { if (threadIdx.x < s) red[threadIdx.x] += red[threadIdx.x + s]; __syncthreads(); }
  if (threadIdx.x == 0) atomicAdd(&scal[1], red[0]);
}

// ---------------- outputs ----------------

__global__ __launch_bounds__(256) void recon_out_kernel(const float* __restrict__ recon, const float* __restrict__ x,
                                                        float* __restrict__ out, float* __restrict__ scal) {
  __shared__ float red[256];
  long i = (long)blockIdx.x * 256 + threadIdx.x;  // 614400
  float r = recon[i];
  out[i] = r;
  float d = r - x[i];
  red[threadIdx.x] = d * d; __syncthreads();
  for (int s = 128; s > 0; s >>= 1) { if (threadIdx.x < s) red[threadIdx.x] += red[threadIdx.x + s]; __syncthreads(); }
  if (threadIdx.x == 0) atomicAdd(&scal[0], red[0]);
}

__global__ void finalize_kernel(const float* __restrict__ scal, float* __restrict__ out) {
  float rl = scal[0] / 4096.0f;
  float el = scal[1] / (float)kZeN;
  out[kScalOff + 0] = rl;
  out[kScalOff + 1] = 0.25f * el;
  out[kScalOff + 2] = el;
}

// ---------------- host orchestration ----------------

extern "C" void kernel_launch(void* const* d_in, const int* in_sizes, int n_in,
                              void* d_out, int out_size, void* d_ws, size_t ws_size,
                              hipStream_t stream) {
  (void)out_size; (void)ws_size;
  // input layout detection: enc_in_w = 76800 elements followed by 512 (enc_in_b)
  int base = 2;
  for (int i = 1; i <= 3 && i + 1 < n_in; ++i) {
    if (in_sizes[i] == 76800 && in_sizes[i + 1] == 512) { base = i; break; }
  }
  const int off = base - 2;

  const float* x          = (const float*)d_in[0];
  const float* enc_in_w   = (const float*)d_in[2 + off];
  const float* enc_in_b   = (const float*)d_in[3 + off];
  const float* enc_qkv_w  = (const float*)d_in[4 + off];
  const float* enc_qkv_b  = (const float*)d_in[5 + off];
  const float* enc_ao_w   = (const float*)d_in[6 + off];
  const float* enc_ao_b   = (const float*)d_in[7 + off];
  const float* enc_ln1_w  = (const float*)d_in[8 + off];
  const float* enc_ln1_b  = (const float*)d_in[9 + off];
  const float* enc_ln2_w  = (const float*)d_in[10 + off];
  const float* enc_ln2_b  = (const float*)d_in[11 + off];
  const float* enc_ff1_w  = (const float*)d_in[12 + off];
  const float* enc_ff1_b  = (const float*)d_in[13 + off];
  const float* enc_ff2_w  = (const float*)d_in[14 + off];
  const float* enc_ff2_b  = (const float*)d_in[15 + off];
  const float* enc_fln_w  = (const float*)d_in[16 + off];
  const float* enc_fln_b  = (const float*)d_in[17 + off];
  const float* enc_conv_w = (const float*)d_in[18 + off];
  const float* enc_conv_b = (const float*)d_in[19 + off];
  const float* codebook   = (const float*)d_in[20 + off];
  const float* dec_in_w   = (const float*)d_in[21 + off];
  const float* dec_in_b   = (const float*)d_in[22 + off];
  const float* dec_up_w   = (const float*)d_in[23 + off];
  const float* dec_up_b   = (const float*)d_in[24 + off];
  const float* query_emb  = (const float*)d_in[25 + off];
  const float* dec_sa_qkv_w = (const float*)d_in[26 + off];
  const float* dec_sa_qkv_b = (const float*)d_in[27 + off];
  const float* dec_sa_o_w   = (const float*)d_in[28 + off];
  const float* dec_sa_o_b   = (const float*)d_in[29 + off];
  const float* dec_ca_qkv_w = (const float*)d_in[30 + off];
  const float* dec_ca_qkv_b = (const float*)d_in[31 + off];
  const float* dec_ca_o_w   = (const float*)d_in[32 + off];
  const float* dec_ca_o_b   = (const float*)d_in[33 + off];
  const float* dec_ln1_w  = (const float*)d_in[34 + off];
  const float* dec_ln1_b  = (const float*)d_in[35 + off];
  const float* dec_ln2_w  = (const float*)d_in[36 + off];
  const float* dec_ln2_b  = (const float*)d_in[37 + off];
  const float* dec_ln3_w  = (const float*)d_in[38 + off];
  const float* dec_ln3_b  = (const float*)d_in[39 + off];
  const float* dec_ff1_w  = (const float*)d_in[40 + off];
  const float* dec_ff1_b  = (const float*)d_in[41 + off];
  const float* dec_ff2_w  = (const float*)d_in[42 + off];
  const float* dec_ff2_b  = (const float*)d_in[43 + off];
  const float* dec_out_w  = (const float*)d_in[44 + off];
  const float* dec_out_b  = (const float*)d_in[45 + off];

  float* outp = (float*)d_out;   // float32 output buffer

  // ---- workspace layout: total ~61 MB ----
  float* wsf  = (float*)d_ws;
  float* SCALp = wsf;                    // 8
  float* CNFp  = wsf + 8;                // 4096 (f32 |c|^2)
  int*   IDXp  = (int*)(wsf + 8 + 4096); // 1024 ints
  float* B3p   = wsf + 8 + 4096 + 1024;  // 2048
  float* PEp   = wsf + 8192;             // 262144
  float* Hp    = PEp + 262144;           // 2097152
  float* Yp    = Hp + 2097152;           // 2097152 (also PV-out, also MEM0)
  float* Qp    = Yp + 2097152;           // 2097152
  float* Kp    = Qp + 2097152;           // 2097152
  float* Vp    = Kp + 2097152;           // 2097152
  float* BIGp  = Vp + 2097152;           // 2097152 (scores/ffn-chunk/W2/W3/recon)
  float* ZEp   = BIGp + 2097152;         // 524288
  float* ZQp   = ZEp + 524288;           // 524288
  float* MEMp  = ZQp + 524288;           // 2097152

  auto gemm = [&](bool f64, const float* A, int lda, const float* W, int ldw, float* C, int ldc,
                  const float* bias, int M, int N, int Kd, float alpha, int flags,
                  int nz = 1, int zDiv = 1,
                  long sAo = 0, long sAi = 0, long sWo = 0, long sWi = 0, long sCo = 0, long sCi = 0) {
    dim3 g((N + 63) / 64, (M + 63) / 64, nz);
    if (f64)
      gemm_kernel<double><<<g, 256, 0, stream>>>(A, lda, sAo, sAi, W, ldw, sWo, sWi, C, ldc, sCo, sCi,
                                                 bias, M, N, Kd, zDiv, alpha, flags);
    else
      gemm_kernel<float><<<g, 256, 0, stream>>>(A, lda, sAo, sAi, W, ldw, sWo, sWi, C, ldc, sCo, sCi,
                                                bias, M, N, Kd, zDiv, alpha, flags);
  };

  auto ln = [&](const float* X, const float* w, const float* b, float* Y, int rows) {
    ln_kernel<<<rows, 256, 0, stream>>>(X, w, b, Y);
  };

  auto attention = [&](bool f64, const float* Qb, const float* Kb, const float* Vb, float* Ob) {
    for (int b = 0; b < kB; ++b) {
      long boff = (long)b * kT * kH;
      gemm(f64, Qb + boff, 512, Kb + boff, 512, BIGp, 512, nullptr,
           512, 512, 64, 0.125f, 0,
           8, 1, 64, 0, 64, 0, (long)kT * kT, 0);
      softmax_rows_kernel<<<8 * kT, 256, 0, stream>>>(BIGp);
      if (f64) pv_kernel<double><<<dim3(8, 1, 8), 256, 0, stream>>>(BIGp, Vb + boff, Ob + boff);
      else     pv_kernel<float><<<dim3(8, 1, 8), 256, 0, stream>>>(BIGp, Vb + boff, Ob + boff);
    }
  };

  auto ffn = [&](bool f64, const float* w1, const float* b1, const float* w2, const float* b2) {
    for (int c = 0; c < 4; ++c) {
      long r0 = (long)c * 1024;
      gemm(f64, Yp + r0 * 512, 512, w1, 512, BIGp, kFF, b1, 1024, kFF, 512, 1.f, 2);
      gemm(f64, BIGp, kFF, w2, kFF, Hp + r0 * 512, 512, b2, 1024, 512, kFF, 1.f, 1);
    }
  };

  // ---- init ----
  zero_scal_kernel<<<1, 256, 0, stream>>>(SCALp);
  pe_kernel<<<1024, 256, 0, stream>>>(PEp);

  // ---- encoder (f64-accumulated) ----
  gemm(true, x, kDP, enc_in_w, kDP, Hp, 512, enc_in_b, kNTOK, 512, kDP, 1.f, 0);
  addpe_kernel<<<8192, 256, 0, stream>>>(Hp, PEp);

  for (int i = 0; i < 2; ++i) {
    ln(Hp, enc_ln1_w + i * 512, enc_ln1_b + i * 512, Yp, kNTOK);
    const float* qkvw = enc_qkv_w + (long)i * 1536 * 512;
    const float* qkvb = enc_qkv_b + i * 1536;
    gemm(true, Yp, 512, qkvw,          512, Qp, 512, qkvb,        kNTOK, 512, 512, 1.f, 0);
    gemm(true, Yp, 512, qkvw + 262144, 512, Kp, 512, qkvb + 512,  kNTOK, 512, 512, 1.f, 0);
    gemm(true, Yp, 512, qkvw + 524288, 512, Vp, 512, qkvb + 1024, kNTOK, 512, 512, 1.f, 0);
    attention(true, Qp, Kp, Vp, Yp);   // Yp free after QKV projections
    gemm(true, Yp, 512, enc_ao_w + (long)i * 262144, 512, Hp, 512, enc_ao_b + i * 512, kNTOK, 512, 512, 1.f, 1);
    ln(Hp, enc_ln2_w + i * 512, enc_ln2_b + i * 512, Yp, kNTOK);
    ffn(true, enc_ff1_w + (long)i * kFF * 512, enc_ff1_b + i * kFF,
        enc_ff2_w + (long)i * 512 * kFF, enc_ff2_b + i * 512);
  }

  // final LN + strided conv (f64 accumulation); permuted conv weight in BIG
  ln(Hp, enc_fln_w, enc_fln_b, Yp, kNTOK);
  perm_encconv_kernel<<<4096, 256, 0, stream>>>(enc_conv_w, BIGp);
  conv_ze_kernel<<<kNLAT, 256, 0, stream>>>(Yp, BIGp, enc_conv_b, ZEp);

  // ---- VQ (f32-bucket emulation of np's distance) ----
  codenorm_f_kernel<<<kK, 256, 0, stream>>>(codebook, CNFp);
  vq_kernel<<<kNLAT / VQROWS, 256, 0, stream>>>(ZEp, codebook, CNFp, IDXp, outp + kIdxOff);
  gather_kernel<<<2048, 256, 0, stream>>>(codebook, IDXp, ZEp, ZQp, outp + kZeOff, SCALp);

  // ---- decoder (f32) ----
  gemm(false, ZQp, 512, dec_in_w, 512, Yp, 512, dec_in_b, kNLAT, 512, 512, 1.f, 0);   // Yp = mem0
  perm_decup_kernel<<<4096, 256, 0, stream>>>(dec_up_w, dec_up_b, BIGp, B3p);
  gemm(false, Yp, 512, BIGp, 512, MEMp, 2048, B3p, kNLAT, 2048, 512, 1.f, 0);         // == 4096x512
  addpe_kernel<<<8192, 256, 0, stream>>>(MEMp, PEp);
  qinit_kernel<<<8192, 256, 0, stream>>>(Hp, query_emb, PEp);

  for (int i = 0; i < 2; ++i) {
    // self-attention
    ln(Hp, dec_ln1_w + i * 512, dec_ln1_b + i * 512, Yp, kNTOK);
    const float* saw = dec_sa_qkv_w + (long)i * 1536 * 512;
    const float* sab = dec_sa_qkv_b + i * 1536;
    gemm(false, Yp, 512, saw,          512, Qp, 512, sab,        kNTOK, 512, 512, 1.f, 0);
    gemm(false, Yp, 512, saw + 262144, 512, Kp, 512, sab + 512,  kNTOK, 512, 512, 1.f, 0);
    gemm(false, Yp, 512, saw + 524288, 512, Vp, 512, sab + 1024, kNTOK, 512, 512, 1.f, 0);
    attention(false, Qp, Kp, Vp, Yp);
    gemm(false, Yp, 512, dec_sa_o_w + (long)i * 262144, 512, Hp, 512, dec_sa_o_b + i * 512, kNTOK, 512, 512, 1.f, 1);
    // cross-attention (kv from MEM, not normalized)
    ln(Hp, dec_ln2_w + i * 512, dec_ln2_b + i * 512, Yp, kNTOK);
    const float* caw = dec_ca_qkv_w + (long)i * 1536 * 512;
    const float* cab = dec_ca_qkv_b + i * 1536;
    gemm(false, Yp,   512, caw,          512, Qp, 512, cab,        kNTOK, 512, 512, 1.f, 0);
    gemm(false, MEMp, 512, caw + 262144, 512, Kp, 512, cab + 512,  kNTOK, 512, 512, 1.f, 0);
    gemm(false, MEMp, 512, caw + 524288, 512, Vp, 512, cab + 1024, kNTOK, 512, 512, 1.f, 0);
    attention(false, Qp, Kp, Vp, Yp);
    gemm(false, Yp, 512, dec_ca_o_w + (long)i * 262144, 512, Hp, 512, dec_ca_o_b + i * 512, kNTOK, 512, 512, 1.f, 1);
    // ffn
    ln(Hp, dec_ln3_w + i * 512, dec_ln3_b + i * 512, Yp, kNTOK);
    ffn(false, dec_ff1_w + (long)i * kFF * 512, dec_ff1_b + i * kFF,
        dec_ff2_w + (long)i * 512 * kFF, dec_ff2_b + i * 512);
  }

  // ---- outputs ----
  gemm(false, Hp, 512, dec_out_w, 512, BIGp, kDP, dec_out_b, kNTOK, kDP, 512, 1.f, 0);
  recon_out_kernel<<<2400, 256, 0, stream>>>(BIGp, x, outp, SCALp);
  finalize_kernel<<<1, 1, 0, stream>>>(SCALp, outp);
}